// Round 1
// baseline (307.724 us; speedup 1.0000x reference)
//
#include <hip/hip_runtime.h>
#include <stdint.h>

#define HDIM 1024
#define NEXP 32
#define IDIM 512
#define TOPK 6
#define NTOK 2048
#define NPAIR (NTOK*TOPK)   // 12288

typedef __attribute__((ext_vector_type(4))) float f32x4;
typedef __attribute__((ext_vector_type(8))) short s16x8;
typedef __attribute__((ext_vector_type(8))) __bf16 bf16x8;

static __device__ __forceinline__ f32x4 mfma16(s16x8 a, s16x8 b, f32x4 c){
  return __builtin_amdgcn_mfma_f32_16x16x32_bf16(
      __builtin_bit_cast(bf16x8, a), __builtin_bit_cast(bf16x8, b), c, 0, 0, 0);
}

static __device__ __forceinline__ unsigned short f2bf(float f){
  union { float f; unsigned u; } v; v.f = f;
  unsigned r = v.u + 0x7fffu + ((v.u >> 16) & 1u);
  return (unsigned short)(r >> 16);
}

// ---- stage a [ROWS x 64] bf16 tile into LDS via global_load_lds -----------
// LDS dest is linear (HW requirement); global source column is pre-XORed so
// that swizzled reads (frag_ld) see the logical layout (rule 21).
template<int ROWS, typename RowFn>
static __device__ __forceinline__ void stage_tile(const short* __restrict__ g, int ldg,
                                                  short* lds, int k0, int tid, RowFn rowOf){
  #pragma unroll
  for (int pss = 0; pss < ROWS/32; ++pss){
    int chunk = pss*256 + tid;          // wave-contiguous: base + lane*16B
    int row   = chunk >> 3;             // 8 x 16B chunks per 128B row
    int kb    = (chunk & 7) << 4;       // linear byte col
    int skb   = kb ^ ((row & 7) << 4);  // pre-swizzled source col
    const short* src = g + (long)rowOf(row)*ldg + k0 + (skb >> 1);
    __builtin_amdgcn_global_load_lds((const __attribute__((address_space(1))) void*)src,
                                     (__attribute__((address_space(3))) void*)(lds + chunk*8),
                                     16, 0, 0);
  }
}

// fragment read: lane holds 8 consecutive k of row (lane&15), k-chunk (lane>>4)*8
static __device__ __forceinline__ s16x8 frag_ld(const short* lds, int row, int ks, int lane){
  int kb  = ks*64 + ((lane >> 4) << 4);
  int off = row*128 + (kb ^ ((row & 7) << 4));
  return *(const s16x8*)(lds + (off >> 1));
}

// ---------------- weight fp32 -> bf16 conversion (+ zero counts) -----------
__global__ void k_convert(const float4* __restrict__ gu, const float4* __restrict__ dn,
                          const float4* __restrict__ sg, const float4* __restrict__ su,
                          const float4* __restrict__ sd,
                          ushort4* __restrict__ bgu, ushort4* __restrict__ bdn,
                          ushort4* __restrict__ bsg, ushort4* __restrict__ bsu,
                          ushort4* __restrict__ bsd, int* __restrict__ counts){
  long i = (long)blockIdx.x*256 + threadIdx.x;
  if (i < NEXP) counts[i] = 0;
  const long NGU = 33554432/4, NDN = 16777216/4, NS = 1048576/4;
  const long tot = NGU + NDN + 3*NS;
  for (; i < tot; i += (long)gridDim.x*256){
    float4 v; ushort4* d; long j = i;
    if (j < NGU){ v = gu[j]; d = bgu + j; }
    else { j -= NGU;
      if (j < NDN){ v = dn[j]; d = bdn + j; }
      else { j -= NDN;
        if (j < NS){ v = sg[j]; d = bsg + j; }
        else { j -= NS;
          if (j < NS){ v = su[j]; d = bsu + j; }
          else { j -= NS; v = sd[j]; d = bsd + j; }
        }
      }
    }
    ushort4 o; o.x = f2bf(v.x); o.y = f2bf(v.y); o.z = f2bf(v.z); o.w = f2bf(v.w);
    *d = o;
  }
}

// ---------------- router: logits, softmax, top-6, counts, x->bf16 ----------
__global__ __launch_bounds__(256) void k_router(const float* __restrict__ x,
    const float* __restrict__ wr, const float* __restrict__ bias,
    short* __restrict__ xb, int* __restrict__ tki, float* __restrict__ tkw,
    int* __restrict__ counts){
  int t = blockIdx.x, tid = threadIdx.x, lane = tid & 63, wid = tid >> 6;
  __shared__ float xs[HDIM];
  __shared__ float lg[NEXP];
  const float4* xr = (const float4*)(x + (long)t*HDIM);
  float4 v = xr[tid];
  ((float4*)xs)[tid] = v;
  ushort4 o; o.x = f2bf(v.x); o.y = f2bf(v.y); o.z = f2bf(v.z); o.w = f2bf(v.w);
  *(ushort4*)(xb + (long)t*HDIM + tid*4) = o;
  __syncthreads();
  #pragma unroll
  for (int j = 0; j < 8; ++j){
    int e = wid*8 + j;
    const float* w = wr + (long)e*HDIM;
    float acc = 0.f;
    for (int k = lane; k < HDIM; k += 64) acc += xs[k]*w[k];
    for (int s = 32; s; s >>= 1) acc += __shfl_xor(acc, s);
    if (lane == 0) lg[e] = acc;
  }
  __syncthreads();
  if (wid == 0){
    float l = (lane < NEXP) ? lg[lane] : -1e30f;
    float m = l;
    for (int s = 32; s; s >>= 1) m = fmaxf(m, __shfl_xor(m, s));
    float p = (lane < NEXP) ? __expf(l - m) : 0.f;
    float sum = p;
    for (int s = 32; s; s >>= 1) sum += __shfl_xor(sum, s);
    p = p / sum;
    float rem = (lane < NEXP) ? (p + bias[lane]) : -1e30f;
    int myidx = 0; float myw = 0.f;
    for (int k = 0; k < TOPK; ++k){
      float vv = rem; int ix = lane;
      for (int s = 32; s; s >>= 1){
        float ov = __shfl_xor(vv, s); int oi = __shfl_xor(ix, s);
        if (ov > vv || (ov == vv && oi < ix)){ vv = ov; ix = oi; }
      }
      float pw = __shfl(p, ix);
      if (lane == ix) rem = -1e30f;
      if (lane == k){ myidx = ix; myw = pw; }
    }
    float s6 = (lane < TOPK) ? myw : 0.f;
    for (int s = 32; s; s >>= 1) s6 += __shfl_xor(s6, s);
    if (lane < TOPK){
      tki[t*TOPK + lane] = myidx;
      tkw[t*TOPK + lane] = myw / fmaxf(s6, 1e-12f);
      atomicAdd(&counts[myidx], 1);
    }
  }
}

__global__ void k_scan(const int* __restrict__ counts, int* __restrict__ offsets,
                       int* __restrict__ cursor){
  if (threadIdx.x == 0){
    int s = 0;
    for (int e = 0; e < NEXP; ++e){ offsets[e] = s; cursor[e] = s; s += counts[e]; }
    offsets[NEXP] = s;
  }
}

__global__ void k_scatter(const int* __restrict__ tki, const float* __restrict__ tkw,
                          int* __restrict__ cursor, int* __restrict__ permt,
                          float* __restrict__ permw){
  int i = blockIdx.x*256 + threadIdx.x;
  if (i < NPAIR){
    int e = tki[i];
    int pos = atomicAdd(&cursor[e], 1);
    permt[pos] = i / TOPK;
    permw[pos] = tkw[i];
  }
}

// ---------------- shared gate+up fused (silu epilogue) ---------------------
__global__ __launch_bounds__(256) void k_gu_shared(const short* __restrict__ xb,
    const short* __restrict__ wg_, const short* __restrict__ wu_, short* __restrict__ sb){
  int n0 = blockIdx.x*64, m0 = blockIdx.y*128;
  int tid = threadIdx.x, lane = tid & 63, wid = tid >> 6, wr = wid >> 1, wc = wid & 1;
  __shared__ short As[128*64], Bg[64*64], Bu[64*64];
  const short* wg = wg_ + (long)n0*HDIM;
  const short* wu = wu_ + (long)n0*HDIM;
  f32x4 z = {0.f,0.f,0.f,0.f};
  f32x4 ag[4][2], au[4][2];
  for (int i=0;i<4;i++) for (int j=0;j<2;j++){ ag[i][j]=z; au[i][j]=z; }
  for (int kt = 0; kt < HDIM/64; ++kt){
    __syncthreads();
    int k0 = kt*64;
    stage_tile<128>(xb, HDIM, As, k0, tid, [&](int r){ return m0 + r; });
    stage_tile<64>(wg, HDIM, Bg, k0, tid, [](int r){ return r; });
    stage_tile<64>(wu, HDIM, Bu, k0, tid, [](int r){ return r; });
    __syncthreads();
    #pragma unroll
    for (int ks = 0; ks < 2; ++ks){
      s16x8 af[4], bg[2], bu[2];
      #pragma unroll
      for (int i = 0; i < 4; ++i) af[i] = frag_ld(As, wr*64 + i*16 + (lane&15), ks, lane);
      #pragma unroll
      for (int j = 0; j < 2; ++j){
        bg[j] = frag_ld(Bg, wc*32 + j*16 + (lane&15), ks, lane);
        bu[j] = frag_ld(Bu, wc*32 + j*16 + (lane&15), ks, lane);
      }
      #pragma unroll
      for (int i = 0; i < 4; ++i)
        #pragma unroll
        for (int j = 0; j < 2; ++j){
          ag[i][j] = mfma16(af[i], bg[j], ag[i][j]);
          au[i][j] = mfma16(af[i], bu[j], au[i][j]);
        }
    }
  }
  #pragma unroll
  for (int i = 0; i < 4; ++i){
    int mrow = m0 + wr*64 + i*16 + ((lane >> 4) << 2);
    #pragma unroll
    for (int j = 0; j < 2; ++j){
      int col = n0 + wc*32 + j*16 + (lane & 15);
      #pragma unroll
      for (int r = 0; r < 4; ++r){
        float gv = ag[i][j][r], uv = au[i][j][r];
        float sv = gv / (1.f + __expf(-gv)) * uv;
        sb[(long)(mrow + r)*1024 + col] = (short)f2bf(sv);
      }
    }
  }
}

// ---------------- expert gate+up fused (gathered A, silu, -> hmid) ---------
__global__ __launch_bounds__(256) void k_gu_expert(const short* __restrict__ xb,
    const short* __restrict__ wgu, const int* __restrict__ offsets,
    const int* __restrict__ permt, short* __restrict__ hmid){
  int e = blockIdx.z, mt = blockIdx.y, nb = blockIdx.x;
  int off = offsets[e], seg = offsets[e+1] - off;
  int m0 = mt*128;
  if (m0 >= seg) return;
  int tid = threadIdx.x, lane = tid & 63, wid = tid >> 6, wr = wid >> 1, wc = wid & 1;
  __shared__ short As[128*64], Bg[64*64], Bu[64*64];
  __shared__ int rowmap[128];
  if (tid < 128) rowmap[tid] = permt[off + min(m0 + tid, seg - 1)];
  int n0 = nb*64;
  const short* wg = wgu + (long)e*1024*HDIM + (long)n0*HDIM;
  const short* wu = wg + (long)IDIM*HDIM;
  f32x4 z = {0.f,0.f,0.f,0.f};
  f32x4 ag[4][2], au[4][2];
  for (int i=0;i<4;i++) for (int j=0;j<2;j++){ ag[i][j]=z; au[i][j]=z; }
  for (int kt = 0; kt < HDIM/64; ++kt){
    __syncthreads();
    int k0 = kt*64;
    stage_tile<128>(xb, HDIM, As, k0, tid, [&](int r){ return rowmap[r]; });
    stage_tile<64>(wg, HDIM, Bg, k0, tid, [](int r){ return r; });
    stage_tile<64>(wu, HDIM, Bu, k0, tid, [](int r){ return r; });
    __syncthreads();
    #pragma unroll
    for (int ks = 0; ks < 2; ++ks){
      s16x8 af[4], bg[2], bu[2];
      #pragma unroll
      for (int i = 0; i < 4; ++i) af[i] = frag_ld(As, wr*64 + i*16 + (lane&15), ks, lane);
      #pragma unroll
      for (int j = 0; j < 2; ++j){
        bg[j] = frag_ld(Bg, wc*32 + j*16 + (lane&15), ks, lane);
        bu[j] = frag_ld(Bu, wc*32 + j*16 + (lane&15), ks, lane);
      }
      #pragma unroll
      for (int i = 0; i < 4; ++i)
        #pragma unroll
        for (int j = 0; j < 2; ++j){
          ag[i][j] = mfma16(af[i], bg[j], ag[i][j]);
          au[i][j] = mfma16(af[i], bu[j], au[i][j]);
        }
    }
  }
  #pragma unroll
  for (int i = 0; i < 4; ++i){
    int mrow = wr*64 + i*16 + ((lane >> 4) << 2);
    #pragma unroll
    for (int j = 0; j < 2; ++j){
      int col = n0 + wc*32 + j*16 + (lane & 15);
      #pragma unroll
      for (int r = 0; r < 4; ++r){
        int m = mrow + r;
        if (m0 + m < seg){
          float gv = ag[i][j][r], uv = au[i][j][r];
          float sv = gv / (1.f + __expf(-gv)) * uv;
          hmid[(long)(off + m0 + m)*IDIM + col] = (short)f2bf(sv);
        }
      }
    }
  }
}

// ---------------- shared down: writes base of d_out ------------------------
__global__ __launch_bounds__(256) void k_down_shared(const short* __restrict__ sb,
    const short* __restrict__ wd, float* __restrict__ out){
  int n0 = blockIdx.x*128, m0 = blockIdx.y*128;
  int tid = threadIdx.x, lane = tid & 63, wid = tid >> 6, wr = wid >> 1, wc = wid & 1;
  __shared__ short As[128*64], Bs[128*64];
  const short* wb = wd + (long)n0*1024;
  f32x4 z = {0.f,0.f,0.f,0.f};
  f32x4 acc[4][4];
  for (int i=0;i<4;i++) for (int j=0;j<4;j++) acc[i][j]=z;
  for (int kt = 0; kt < 1024/64; ++kt){
    __syncthreads();
    int k0 = kt*64;
    stage_tile<128>(sb, 1024, As, k0, tid, [&](int r){ return m0 + r; });
    stage_tile<128>(wb, 1024, Bs, k0, tid, [](int r){ return r; });
    __syncthreads();
    #pragma unroll
    for (int ks = 0; ks < 2; ++ks){
      s16x8 af[4], bf[4];
      #pragma unroll
      for (int i = 0; i < 4; ++i){
        af[i] = frag_ld(As, wr*64 + i*16 + (lane&15), ks, lane);
        bf[i] = frag_ld(Bs, wc*64 + i*16 + (lane&15), ks, lane);
      }
      #pragma unroll
      for (int i = 0; i < 4; ++i)
        #pragma unroll
        for (int j = 0; j < 4; ++j)
          acc[i][j] = mfma16(af[i], bf[j], acc[i][j]);
    }
  }
  #pragma unroll
  for (int i = 0; i < 4; ++i){
    int mrow = m0 + wr*64 + i*16 + ((lane >> 4) << 2);
    #pragma unroll
    for (int j = 0; j < 4; ++j){
      int col = n0 + wc*64 + j*16 + (lane & 15);
      #pragma unroll
      for (int r = 0; r < 4; ++r)
        out[(long)(mrow + r)*HDIM + col] = acc[i][j][r];
    }
  }
}

// ---------------- expert down: atomicAdd w*acc onto d_out ------------------
__global__ __launch_bounds__(256) void k_down_expert(const short* __restrict__ hmid,
    const short* __restrict__ wdn, const int* __restrict__ offsets,
    const int* __restrict__ permt, const float* __restrict__ permw,
    float* __restrict__ out){
  int e = blockIdx.z, mt = blockIdx.y, nb = blockIdx.x;
  int off = offsets[e], seg = offsets[e+1] - off;
  int m0 = mt*128;
  if (m0 >= seg) return;
  int tid = threadIdx.x, lane = tid & 63, wid = tid >> 6, wr = wid >> 1, wc = wid & 1;
  int n0 = nb*128;
  __shared__ short As[128*64], Bs[128*64];
  const short* wb = wdn + (long)e*HDIM*IDIM + (long)n0*IDIM;
  f32x4 z = {0.f,0.f,0.f,0.f};
  f32x4 acc[4][4];
  for (int i=0;i<4;i++) for (int j=0;j<4;j++) acc[i][j]=z;
  for (int kt = 0; kt < IDIM/64; ++kt){
    __syncthreads();
    int k0 = kt*64;
    stage_tile<128>(hmid, IDIM, As, k0, tid, [&](int r){ return off + min(m0 + r, seg - 1); });
    stage_tile<128>(wb, IDIM, Bs, k0, tid, [](int r){ return r; });
    __syncthreads();
    #pragma unroll
    for (int ks = 0; ks < 2; ++ks){
      s16x8 af[4], bf[4];
      #pragma unroll
      for (int i = 0; i < 4; ++i){
        af[i] = frag_ld(As, wr*64 + i*16 + (lane&15), ks, lane);
        bf[i] = frag_ld(Bs, wc*64 + i*16 + (lane&15), ks, lane);
      }
      #pragma unroll
      for (int i = 0; i < 4; ++i)
        #pragma unroll
        for (int j = 0; j < 4; ++j)
          acc[i][j] = mfma16(af[i], bf[j], acc[i][j]);
    }
  }
  #pragma unroll
  for (int i = 0; i < 4; ++i){
    int mrow = wr*64 + i*16 + ((lane >> 4) << 2);
    #pragma unroll
    for (int r = 0; r < 4; ++r){
      int m = mrow + r;
      if (m0 + m < seg){
        int p = off + m0 + m;
        int t = permt[p];
        float w = permw[p];
        #pragma unroll
        for (int j = 0; j < 4; ++j){
          int col = n0 + wc*64 + j*16 + (lane & 15);
          atomicAdd(&out[(long)t*HDIM + col], w*acc[i][j][r]);
        }
      }
    }
  }
}

extern "C" void kernel_launch(void* const* d_in, const int* in_sizes, int n_in,
                              void* d_out, int out_size, void* d_ws, size_t ws_size,
                              hipStream_t stream){
  const float* x    = (const float*)d_in[0];
  const float* rw   = (const float*)d_in[1];
  const float* bias = (const float*)d_in[2];
  const float* wgu  = (const float*)d_in[3];
  const float* wdn  = (const float*)d_in[4];
  const float* wsg  = (const float*)d_in[5];
  const float* wsu  = (const float*)d_in[6];
  const float* wsd  = (const float*)d_in[7];
  float* out = (float*)d_out;

  char* ws = (char*)d_ws;
  size_t o = 0;
  auto alloc = [&](size_t bytes){ void* p = ws + o; o += (bytes + 255) & ~(size_t)255; return p; };
  short* bgu  = (short*)alloc(67108864);   // [E,2I,H] bf16
  short* bdn  = (short*)alloc(33554432);   // [E,H,I]  bf16
  short* bsg  = (short*)alloc(2097152);
  short* bsu  = (short*)alloc(2097152);
  short* bsd  = (short*)alloc(2097152);
  short* xb   = (short*)alloc(4194304);    // [T,H] bf16
  short* sb   = (short*)alloc(4194304);    // [T,IS] bf16
  short* hmid = (short*)alloc(12582912);   // [P,I] bf16
  int*   tki  = (int*)alloc(NPAIR*4);
  float* tkw  = (float*)alloc(NPAIR*4);
  int*   counts  = (int*)alloc(256);
  int*   offsets = (int*)alloc(256);
  int*   cursor  = (int*)alloc(256);
  int*   permt   = (int*)alloc(NPAIR*4);
  float* permw   = (float*)alloc(NPAIR*4);
  (void)ws_size; (void)in_sizes; (void)n_in; (void)out_size;

  k_convert<<<dim3(2048), dim3(256), 0, stream>>>((const float4*)wgu, (const float4*)wdn,
      (const float4*)wsg, (const float4*)wsu, (const float4*)wsd,
      (ushort4*)bgu, (ushort4*)bdn, (ushort4*)bsg, (ushort4*)bsu, (ushort4*)bsd, counts);
  k_router<<<dim3(NTOK), dim3(256), 0, stream>>>(x, rw, bias, xb, tki, tkw, counts);
  k_scan<<<dim3(1), dim3(64), 0, stream>>>(counts, offsets, cursor);
  k_scatter<<<dim3((NPAIR+255)/256), dim3(256), 0, stream>>>(tki, tkw, cursor, permt, permw);
  k_gu_shared<<<dim3(16, 16), dim3(256), 0, stream>>>(xb, bsg, bsu, sb);
  k_gu_expert<<<dim3(8, 16, 32), dim3(256), 0, stream>>>(xb, bgu, offsets, permt, hmid);
  k_down_shared<<<dim3(8, 16), dim3(256), 0, stream>>>(sb, bsd, out);
  k_down_expert<<<dim3(8, 16, 32), dim3(256), 0, stream>>>(hmid, bdn, offsets, permt, permw, out);
}

// Round 2
// 289.516 us; speedup vs baseline: 1.0629x; 1.0629x over previous
//
#include <hip/hip_runtime.h>
#include <stdint.h>

#define HDIM 1024
#define NEXP 32
#define IDIM 512
#define TOPK 6
#define NTOK 2048
#define NPAIR (NTOK*TOPK)   // 12288

typedef __attribute__((ext_vector_type(4))) float f32x4;
typedef __attribute__((ext_vector_type(8))) short s16x8;
typedef __attribute__((ext_vector_type(8))) __bf16 bf16x8;

static __device__ __forceinline__ f32x4 mfma16(s16x8 a, s16x8 b, f32x4 c){
  return __builtin_amdgcn_mfma_f32_16x16x32_bf16(
      __builtin_bit_cast(bf16x8, a), __builtin_bit_cast(bf16x8, b), c, 0, 0, 0);
}

static __device__ __forceinline__ unsigned short f2bf(float f){
  union { float f; unsigned u; } v; v.f = f;
  unsigned r = v.u + 0x7fffu + ((v.u >> 16) & 1u);
  return (unsigned short)(r >> 16);
}

// ---- stage a [ROWS x 64] bf16 tile into LDS via global_load_lds -----------
// LDS dest is linear (HW requirement); global source column is pre-XORed so
// that swizzled reads (frag_ld) see the logical layout (rule 21).
template<int ROWS, typename RowFn>
static __device__ __forceinline__ void stage_tile(const short* __restrict__ g, int ldg,
                                                  short* lds, int k0, int tid, RowFn rowOf){
  #pragma unroll
  for (int pss = 0; pss < ROWS/32; ++pss){
    int chunk = pss*256 + tid;          // wave-contiguous: base + lane*16B
    int row   = chunk >> 3;             // 8 x 16B chunks per 128B row
    int kb    = (chunk & 7) << 4;       // linear byte col
    int skb   = kb ^ ((row & 7) << 4);  // pre-swizzled source col
    const short* src = g + (long)rowOf(row)*ldg + k0 + (skb >> 1);
    __builtin_amdgcn_global_load_lds((const __attribute__((address_space(1))) void*)src,
                                     (__attribute__((address_space(3))) void*)(lds + chunk*8),
                                     16, 0, 0);
  }
}

// ---- stage a [ROWS x 64] tile from FP32 source, converting to bf16 --------
// reg-staging: 2x float4 load -> f2bf -> one ds_write_b128 at the swizzled
// offset (write-side swizzle matches frag_ld's read-side XOR; rule 21).
template<int ROWS>
static __device__ __forceinline__ void stage_f32(const float* __restrict__ g, int ldg,
                                                 short* lds, int k0, int tid){
  #pragma unroll
  for (int pss = 0; pss < ROWS/32; ++pss){
    int chunk = pss*256 + tid;          // 16B bf16 chunk = 8 elems
    int row   = chunk >> 3;
    int kc    = (chunk & 7) * 8;        // element col within 64
    const float4* src = (const float4*)(g + (long)row*ldg + k0 + kc);
    float4 v0 = src[0], v1 = src[1];
    s16x8 o2;
    o2[0]=(short)f2bf(v0.x); o2[1]=(short)f2bf(v0.y); o2[2]=(short)f2bf(v0.z); o2[3]=(short)f2bf(v0.w);
    o2[4]=(short)f2bf(v1.x); o2[5]=(short)f2bf(v1.y); o2[6]=(short)f2bf(v1.z); o2[7]=(short)f2bf(v1.w);
    int kb  = (chunk & 7) << 4;
    int off = row*128 + (kb ^ ((row & 7) << 4));
    *(s16x8*)(lds + (off >> 1)) = o2;
  }
}

// fragment read: lane holds 8 consecutive k of row (lane&15), k-chunk (lane>>4)*8
static __device__ __forceinline__ s16x8 frag_ld(const short* lds, int row, int ks, int lane){
  int kb  = ks*64 + ((lane >> 4) << 4);
  int off = row*128 + (kb ^ ((row & 7) << 4));
  return *(const s16x8*)(lds + (off >> 1));
}

__global__ void k_zero(int* __restrict__ counts){
  if (threadIdx.x < NEXP) counts[threadIdx.x] = 0;
}

// ---------------- router: logits, softmax, top-6, counts, x->bf16 ----------
__global__ __launch_bounds__(256) void k_router(const float* __restrict__ x,
    const float* __restrict__ wr, const float* __restrict__ bias,
    short* __restrict__ xb, int* __restrict__ tki, float* __restrict__ tkw,
    int* __restrict__ counts){
  int t = blockIdx.x, tid = threadIdx.x, lane = tid & 63, wid = tid >> 6;
  __shared__ float xs[HDIM];
  __shared__ float lg[NEXP];
  const float4* xr = (const float4*)(x + (long)t*HDIM);
  float4 v = xr[tid];
  ((float4*)xs)[tid] = v;
  ushort4 o; o.x = f2bf(v.x); o.y = f2bf(v.y); o.z = f2bf(v.z); o.w = f2bf(v.w);
  *(ushort4*)(xb + (long)t*HDIM + tid*4) = o;
  __syncthreads();
  #pragma unroll
  for (int j = 0; j < 8; ++j){
    int e = wid*8 + j;
    const float* w = wr + (long)e*HDIM;
    float acc = 0.f;
    for (int k = lane; k < HDIM; k += 64) acc += xs[k]*w[k];
    for (int s = 32; s; s >>= 1) acc += __shfl_xor(acc, s);
    if (lane == 0) lg[e] = acc;
  }
  __syncthreads();
  if (wid == 0){
    float l = (lane < NEXP) ? lg[lane] : -1e30f;
    float m = l;
    for (int s = 32; s; s >>= 1) m = fmaxf(m, __shfl_xor(m, s));
    float p = (lane < NEXP) ? __expf(l - m) : 0.f;
    float sum = p;
    for (int s = 32; s; s >>= 1) sum += __shfl_xor(sum, s);
    p = p / sum;
    float rem = (lane < NEXP) ? (p + bias[lane]) : -1e30f;
    int myidx = 0; float myw = 0.f;
    for (int k = 0; k < TOPK; ++k){
      float vv = rem; int ix = lane;
      for (int s = 32; s; s >>= 1){
        float ov = __shfl_xor(vv, s); int oi = __shfl_xor(ix, s);
        if (ov > vv || (ov == vv && oi < ix)){ vv = ov; ix = oi; }
      }
      float pw = __shfl(p, ix);
      if (lane == ix) rem = -1e30f;
      if (lane == k){ myidx = ix; myw = pw; }
    }
    float s6 = (lane < TOPK) ? myw : 0.f;
    for (int s = 32; s; s >>= 1) s6 += __shfl_xor(s6, s);
    if (lane < TOPK){
      tki[t*TOPK + lane] = myidx;
      tkw[t*TOPK + lane] = myw / fmaxf(s6, 1e-12f);
      atomicAdd(&counts[myidx], 1);
    }
  }
}

__global__ void k_scan(const int* __restrict__ counts, int* __restrict__ offsets,
                       int* __restrict__ cursor){
  if (threadIdx.x == 0){
    int s = 0;
    for (int e = 0; e < NEXP; ++e){ offsets[e] = s; cursor[e] = s; s += counts[e]; }
    offsets[NEXP] = s;
  }
}

__global__ void k_scatter(const int* __restrict__ tki, const float* __restrict__ tkw,
                          int* __restrict__ cursor, int* __restrict__ permt,
                          float* __restrict__ permw){
  int i = blockIdx.x*256 + threadIdx.x;
  if (i < NPAIR){
    int e = tki[i];
    int pos = atomicAdd(&cursor[e], 1);
    permt[pos] = i / TOPK;
    permw[pos] = tkw[i];
  }
}

// ---------------- shared gate+up fused (silu epilogue) ---------------------
__global__ __launch_bounds__(256) void k_gu_shared(const short* __restrict__ xb,
    const float* __restrict__ wg_, const float* __restrict__ wu_, short* __restrict__ sb){
  int n0 = blockIdx.x*64, m0 = blockIdx.y*128;
  int tid = threadIdx.x, lane = tid & 63, wid = tid >> 6, wr = wid >> 1, wc = wid & 1;
  __shared__ short As[128*64], Bg[64*64], Bu[64*64];
  const float* wg = wg_ + (long)n0*HDIM;
  const float* wu = wu_ + (long)n0*HDIM;
  f32x4 z = {0.f,0.f,0.f,0.f};
  f32x4 ag[4][2], au[4][2];
  for (int i=0;i<4;i++) for (int j=0;j<2;j++){ ag[i][j]=z; au[i][j]=z; }
  for (int kt = 0; kt < HDIM/64; ++kt){
    __syncthreads();
    int k0 = kt*64;
    stage_tile<128>(xb, HDIM, As, k0, tid, [&](int r){ return m0 + r; });
    stage_f32<64>(wg, HDIM, Bg, k0, tid);
    stage_f32<64>(wu, HDIM, Bu, k0, tid);
    __syncthreads();
    #pragma unroll
    for (int ks = 0; ks < 2; ++ks){
      s16x8 af[4], bg[2], bu[2];
      #pragma unroll
      for (int i = 0; i < 4; ++i) af[i] = frag_ld(As, wr*64 + i*16 + (lane&15), ks, lane);
      #pragma unroll
      for (int j = 0; j < 2; ++j){
        bg[j] = frag_ld(Bg, wc*32 + j*16 + (lane&15), ks, lane);
        bu[j] = frag_ld(Bu, wc*32 + j*16 + (lane&15), ks, lane);
      }
      #pragma unroll
      for (int i = 0; i < 4; ++i)
        #pragma unroll
        for (int j = 0; j < 2; ++j){
          ag[i][j] = mfma16(af[i], bg[j], ag[i][j]);
          au[i][j] = mfma16(af[i], bu[j], au[i][j]);
        }
    }
  }
  #pragma unroll
  for (int i = 0; i < 4; ++i){
    int mrow = m0 + wr*64 + i*16 + ((lane >> 4) << 2);
    #pragma unroll
    for (int j = 0; j < 2; ++j){
      int col = n0 + wc*32 + j*16 + (lane & 15);
      #pragma unroll
      for (int r = 0; r < 4; ++r){
        float gv = ag[i][j][r], uv = au[i][j][r];
        float sv = gv / (1.f + __expf(-gv)) * uv;
        sb[(long)(mrow + r)*1024 + col] = (short)f2bf(sv);
      }
    }
  }
}

// ---------------- expert gate+up fused (gathered A, silu, -> hmid) ---------
__global__ __launch_bounds__(256) void k_gu_expert(const short* __restrict__ xb,
    const float* __restrict__ wgu, const int* __restrict__ offsets,
    const int* __restrict__ permt, short* __restrict__ hmid){
  int e = blockIdx.z, mt = blockIdx.y, nb = blockIdx.x;
  int off = offsets[e], seg = offsets[e+1] - off;
  int m0 = mt*128;
  if (m0 >= seg) return;
  int tid = threadIdx.x, lane = tid & 63, wid = tid >> 6, wr = wid >> 1, wc = wid & 1;
  __shared__ short As[128*64], Bg[64*64], Bu[64*64];
  __shared__ int rowmap[128];
  if (tid < 128) rowmap[tid] = permt[off + min(m0 + tid, seg - 1)];
  int n0 = nb*64;
  const float* wg = wgu + (long)e*1024*HDIM + (long)n0*HDIM;
  const float* wu = wg + (long)IDIM*HDIM;
  f32x4 z = {0.f,0.f,0.f,0.f};
  f32x4 ag[4][2], au[4][2];
  for (int i=0;i<4;i++) for (int j=0;j<2;j++){ ag[i][j]=z; au[i][j]=z; }
  for (int kt = 0; kt < HDIM/64; ++kt){
    __syncthreads();
    int k0 = kt*64;
    stage_tile<128>(xb, HDIM, As, k0, tid, [&](int r){ return rowmap[r]; });
    stage_f32<64>(wg, HDIM, Bg, k0, tid);
    stage_f32<64>(wu, HDIM, Bu, k0, tid);
    __syncthreads();
    #pragma unroll
    for (int ks = 0; ks < 2; ++ks){
      s16x8 af[4], bg[2], bu[2];
      #pragma unroll
      for (int i = 0; i < 4; ++i) af[i] = frag_ld(As, wr*64 + i*16 + (lane&15), ks, lane);
      #pragma unroll
      for (int j = 0; j < 2; ++j){
        bg[j] = frag_ld(Bg, wc*32 + j*16 + (lane&15), ks, lane);
        bu[j] = frag_ld(Bu, wc*32 + j*16 + (lane&15), ks, lane);
      }
      #pragma unroll
      for (int i = 0; i < 4; ++i)
        #pragma unroll
        for (int j = 0; j < 2; ++j){
          ag[i][j] = mfma16(af[i], bg[j], ag[i][j]);
          au[i][j] = mfma16(af[i], bu[j], au[i][j]);
        }
    }
  }
  #pragma unroll
  for (int i = 0; i < 4; ++i){
    int mrow = wr*64 + i*16 + ((lane >> 4) << 2);
    #pragma unroll
    for (int j = 0; j < 2; ++j){
      int col = n0 + wc*32 + j*16 + (lane & 15);
      #pragma unroll
      for (int r = 0; r < 4; ++r){
        int m = mrow + r;
        if (m0 + m < seg){
          float gv = ag[i][j][r], uv = au[i][j][r];
          float sv = gv / (1.f + __expf(-gv)) * uv;
          hmid[(long)(off + m0 + m)*IDIM + col] = (short)f2bf(sv);
        }
      }
    }
  }
}

// ---------------- shared down: writes base of d_out ------------------------
__global__ __launch_bounds__(256) void k_down_shared(const short* __restrict__ sb,
    const float* __restrict__ wd, float* __restrict__ out){
  int n0 = blockIdx.x*128, m0 = blockIdx.y*128;
  int tid = threadIdx.x, lane = tid & 63, wid = tid >> 6, wr = wid >> 1, wc = wid & 1;
  __shared__ short As[128*64], Bs[128*64];
  const float* wb = wd + (long)n0*1024;
  f32x4 z = {0.f,0.f,0.f,0.f};
  f32x4 acc[4][4];
  for (int i=0;i<4;i++) for (int j=0;j<4;j++) acc[i][j]=z;
  for (int kt = 0; kt < 1024/64; ++kt){
    __syncthreads();
    int k0 = kt*64;
    stage_tile<128>(sb, 1024, As, k0, tid, [&](int r){ return m0 + r; });
    stage_f32<128>(wb, 1024, Bs, k0, tid);
    __syncthreads();
    #pragma unroll
    for (int ks = 0; ks < 2; ++ks){
      s16x8 af[4], bf[4];
      #pragma unroll
      for (int i = 0; i < 4; ++i){
        af[i] = frag_ld(As, wr*64 + i*16 + (lane&15), ks, lane);
        bf[i] = frag_ld(Bs, wc*64 + i*16 + (lane&15), ks, lane);
      }
      #pragma unroll
      for (int i = 0; i < 4; ++i)
        #pragma unroll
        for (int j = 0; j < 4; ++j)
          acc[i][j] = mfma16(af[i], bf[j], acc[i][j]);
    }
  }
  #pragma unroll
  for (int i = 0; i < 4; ++i){
    int mrow = m0 + wr*64 + i*16 + ((lane >> 4) << 2);
    #pragma unroll
    for (int j = 0; j < 4; ++j){
      int col = n0 + wc*64 + j*16 + (lane & 15);
      #pragma unroll
      for (int r = 0; r < 4; ++r)
        out[(long)(mrow + r)*HDIM + col] = acc[i][j][r];
    }
  }
}

// ---------------- expert down: atomicAdd w*acc onto d_out ------------------
__global__ __launch_bounds__(256) void k_down_expert(const short* __restrict__ hmid,
    const float* __restrict__ wdn, const int* __restrict__ offsets,
    const int* __restrict__ permt, const float* __restrict__ permw,
    float* __restrict__ out){
  int e = blockIdx.z, mt = blockIdx.y, nb = blockIdx.x;
  int off = offsets[e], seg = offsets[e+1] - off;
  int m0 = mt*128;
  if (m0 >= seg) return;
  int tid = threadIdx.x, lane = tid & 63, wid = tid >> 6, wr = wid >> 1, wc = wid & 1;
  int n0 = nb*128;
  __shared__ short As[128*64], Bs[128*64];
  const float* wb = wdn + (long)e*HDIM*IDIM + (long)n0*IDIM;
  f32x4 z = {0.f,0.f,0.f,0.f};
  f32x4 acc[4][4];
  for (int i=0;i<4;i++) for (int j=0;j<4;j++) acc[i][j]=z;
  for (int kt = 0; kt < IDIM/64; ++kt){
    __syncthreads();
    int k0 = kt*64;
    stage_tile<128>(hmid, IDIM, As, k0, tid, [&](int r){ return off + min(m0 + r, seg - 1); });
    stage_f32<128>(wb, IDIM, Bs, k0, tid);
    __syncthreads();
    #pragma unroll
    for (int ks = 0; ks < 2; ++ks){
      s16x8 af[4], bf[4];
      #pragma unroll
      for (int i = 0; i < 4; ++i){
        af[i] = frag_ld(As, wr*64 + i*16 + (lane&15), ks, lane);
        bf[i] = frag_ld(Bs, wc*64 + i*16 + (lane&15), ks, lane);
      }
      #pragma unroll
      for (int i = 0; i < 4; ++i)
        #pragma unroll
        for (int j = 0; j < 4; ++j)
          acc[i][j] = mfma16(af[i], bf[j], acc[i][j]);
    }
  }
  #pragma unroll
  for (int i = 0; i < 4; ++i){
    int mrow = wr*64 + i*16 + ((lane >> 4) << 2);
    #pragma unroll
    for (int r = 0; r < 4; ++r){
      int m = mrow + r;
      if (m0 + m < seg){
        int p = off + m0 + m;
        int t = permt[p];
        float w = permw[p];
        #pragma unroll
        for (int j = 0; j < 4; ++j){
          int col = n0 + wc*64 + j*16 + (lane & 15);
          atomicAdd(&out[(long)t*HDIM + col], w*acc[i][j][r]);
        }
      }
    }
  }
}

extern "C" void kernel_launch(void* const* d_in, const int* in_sizes, int n_in,
                              void* d_out, int out_size, void* d_ws, size_t ws_size,
                              hipStream_t stream){
  const float* x    = (const float*)d_in[0];
  const float* rw   = (const float*)d_in[1];
  const float* bias = (const float*)d_in[2];
  const float* wgu  = (const float*)d_in[3];
  const float* wdn  = (const float*)d_in[4];
  const float* wsg  = (const float*)d_in[5];
  const float* wsu  = (const float*)d_in[6];
  const float* wsd  = (const float*)d_in[7];
  float* out = (float*)d_out;

  char* ws = (char*)d_ws;
  size_t o = 0;
  auto alloc = [&](size_t bytes){ void* p = ws + o; o += (bytes + 255) & ~(size_t)255; return p; };
  short* xb   = (short*)alloc(4194304);    // [T,H] bf16
  short* sb   = (short*)alloc(4194304);    // [T,IS] bf16
  short* hmid = (short*)alloc(12582912);   // [P,I] bf16
  int*   tki  = (int*)alloc(NPAIR*4);
  float* tkw  = (float*)alloc(NPAIR*4);
  int*   counts  = (int*)alloc(256);
  int*   offsets = (int*)alloc(256);
  int*   cursor  = (int*)alloc(256);
  int*   permt   = (int*)alloc(NPAIR*4);
  float* permw   = (float*)alloc(NPAIR*4);
  (void)ws_size; (void)in_sizes; (void)n_in; (void)out_size;

  k_zero<<<dim3(1), dim3(64), 0, stream>>>(counts);
  k_router<<<dim3(NTOK), dim3(256), 0, stream>>>(x, rw, bias, xb, tki, tkw, counts);
  k_scan<<<dim3(1), dim3(64), 0, stream>>>(counts, offsets, cursor);
  k_scatter<<<dim3((NPAIR+255)/256), dim3(256), 0, stream>>>(tki, tkw, cursor, permt, permw);
  k_gu_shared<<<dim3(16, 16), dim3(256), 0, stream>>>(xb, wsg, wsu, sb);
  k_gu_expert<<<dim3(8, 16, 32), dim3(256), 0, stream>>>(xb, wgu, offsets, permt, hmid);
  k_down_shared<<<dim3(8, 16), dim3(256), 0, stream>>>(sb, wsd, out);
  k_down_expert<<<dim3(8, 16, 32), dim3(256), 0, stream>>>(hmid, wdn, offsets, permt, permw, out);
}